// Round 10
// baseline (281.456 us; speedup 1.0000x reference)
//
#include <hip/hip_runtime.h>

typedef __bf16 bf16x8 __attribute__((ext_vector_type(8)));
typedef float  f32x4  __attribute__((ext_vector_type(4)));

constexpr int MDIM = 65536, NDIM = 1152, KDIM = 768;
constexpr int NBN = 9;                    // N / 128
constexpr int NKT = 24;                   // K / 32
constexpr int GRID2 = (MDIM / 256) * NBN; // 2304 (div by 8)
constexpr int FBGRID = (MDIM / 128) * NBN;// 4608

__device__ __forceinline__ void gload16(const void* g, void* l) {
  __builtin_amdgcn_global_load_lds(
      (const __attribute__((address_space(1))) void*)g,
      (__attribute__((address_space(3))) void*)l, 16, 0, 0);
}

__device__ __forceinline__ unsigned pk2(float x, float y) {
  __bf16 a = (__bf16)x, b = (__bf16)y;
  return (unsigned)__builtin_bit_cast(unsigned short, a) |
         ((unsigned)__builtin_bit_cast(unsigned short, b) << 16);
}

// ---------------- fp32 -> bf16 swizzled-LDS-image repack (identical to R3/R8) -------
__global__ __launch_bounds__(256)
void repack_kernel(const float* __restrict__ in, __bf16* __restrict__ out) {
  const int c    = blockIdx.x * 256 + threadIdx.x;
  const int c_in = c & 511;        // chunk within 8KB image
  const int img  = c >> 9;
  const int kt   = img % NKT;
  const int pan  = img / NKT;      // 128-row panel index
  const int o = c_in * 16;         // swizzled (physical) offset
  const int u = (o >> 6) & 7;
  const int a = o ^ ((u ^ (u >> 2)) << 4);
  const int r = a >> 6;            // tile row 0..127
  const int p = (a >> 4) & 3;      // 16B part within row
  const float* src = in + (size_t)(pan * 128 + r) * KDIM + kt * 32 + p * 8;
  const float4 x = *reinterpret_cast<const float4*>(src);
  const float4 y = *reinterpret_cast<const float4*>(src + 4);
  uint4 r4;
  r4.x = pk2(x.x, x.y); r4.y = pk2(x.z, x.w);
  r4.z = pk2(y.x, y.y); r4.w = pk2(y.z, y.w);
  *reinterpret_cast<uint4*>(out + (size_t)c * 8) = r4;
}

// ---------- main GEMM: 256x128 tile, 8 waves, counted-vmcnt cross-barrier staging ----
// LDS (64 KB): A bufs 3 x 16 KB at 0/16K/32K (each = two 8KB sub-images),
//              B bufs 2 x 8 KB at 48K/56K. Epilogue Cs (32 KB fp32) aliases A0+A1.
__global__ __launch_bounds__(512, 4)
void gemm_8w_kernel(const __bf16* __restrict__ Aimg,  // [512][24][8KB] swizzled images
                    const __bf16* __restrict__ Bimg,  // [9][24][8KB]
                    const int*   __restrict__ ss,
                    const float* __restrict__ bias,
                    const float* __restrict__ pos,
                    float* __restrict__ out) {
  __shared__ __align__(16) unsigned char SM[65536];
  char* smc = reinterpret_cast<char*>(SM);

  const int tid  = threadIdx.x;
  const int lane = tid & 63;
  const int wid  = tid >> 6;      // 0..7
  const int wr   = wid >> 1;      // 0..3 (M)
  const int wc   = wid & 1;       // 0..1 (N)

  const int bidh = blockIdx.x;
  const int bid  = (bidh & 7) * (GRID2 / 8) + (bidh >> 3);
  const int bm   = bid / NBN;     // 0..255 (256-row panel)
  const int bn   = bid % NBN;

  auto stageA = [&](int kt, int abuf) {      // 2 gload16 (two 8KB sub-images)
    const __bf16* i0 = Aimg + ((size_t)((bm * 2 + 0) * NKT + kt) << 12);
    const __bf16* i1 = Aimg + ((size_t)((bm * 2 + 1) * NKT + kt) << 12);
    char* d = smc + abuf * 16384;
    gload16(i0 + tid * 8, d + tid * 16);
    gload16(i1 + tid * 8, d + 8192 + tid * 16);
  };
  auto stageB = [&](int kt, int bbuf) {      // 1 gload16
    const __bf16* ib = Bimg + ((size_t)(bn * NKT + kt) << 12);
    gload16(ib + tid * 8, smc + 49152 + bbuf * 8192 + tid * 16);
  };

  f32x4 acc[4][4];
#pragma unroll
  for (int i = 0; i < 4; ++i)
#pragma unroll
    for (int j = 0; j < 4; ++j) acc[i][j] = (f32x4)0.0f;

  const int fr = lane & 15;
  const int kg = lane >> 4;
  // A: global row = wr*64 + mf*16 + fr -> sub-image wr>>1, row128 = (wr&1)*64+mf*16+fr
  const int abase = (wr >> 1) * 8192 +
                    (((((wr & 1) * 64 + fr) * 64) + kg * 16) ^ ((fr & 7) << 4));
  const int bbase = (((wc * 64 + fr) * 64) + kg * 16) ^ ((fr & 7) << 4);

  auto compute = [&](int abuf, int bbuf) {
    const char* pa = smc + abuf * 16384 + abase;
    const char* pb = smc + 49152 + bbuf * 8192 + bbase;
    bf16x8 af[4], bfv[4];
#pragma unroll
    for (int mf = 0; mf < 4; ++mf)
      af[mf] = *reinterpret_cast<const bf16x8*>(pa + mf * 1024);
#pragma unroll
    for (int nf = 0; nf < 4; ++nf)
      bfv[nf] = *reinterpret_cast<const bf16x8*>(pb + nf * 1024);
    __builtin_amdgcn_s_setprio(1);
#pragma unroll
    for (int mf = 0; mf < 4; ++mf)
#pragma unroll
      for (int nf = 0; nf < 4; ++nf)
        acc[mf][nf] = __builtin_amdgcn_mfma_f32_16x16x32_bf16(af[mf], bfv[nf], acc[mf][nf], 0, 0, 0);
    __builtin_amdgcn_s_setprio(0);
  };

  // Per iter kt: [wait own stage(kt) landed: vmcnt(2) leaves A(kt+1) in flight]
  // -> barrier (all waves' loads landed) -> issue B(kt+1), A(kt+2) -> compute.
  // Writes target buffers whose last readers finished before this barrier.
#define K_ITER(KT, AB, BB, IA, IB, VMS)                                  \
  {                                                                      \
    asm volatile("s_waitcnt vmcnt(" VMS ")" ::: "memory");               \
    __builtin_amdgcn_s_barrier();                                        \
    __builtin_amdgcn_sched_barrier(0);                                   \
    if (IB) stageB((KT) + 1, ((KT) + 1) & 1);                            \
    if (IA) stageA((KT) + 2, ((KT) + 2) % 3);                            \
    compute(AB, BB);                                                     \
  }

  stageA(0, 0);            // issue order: A0(2), B0(1), A1(2)
  stageB(0, 0);
  stageA(1, 1);
  for (int k6 = 0; k6 < 18; k6 += 6) {
    K_ITER(k6 + 0, 0, 0, true, true, "2");
    K_ITER(k6 + 1, 1, 1, true, true, "2");
    K_ITER(k6 + 2, 2, 0, true, true, "2");
    K_ITER(k6 + 3, 0, 1, true, true, "2");
    K_ITER(k6 + 4, 1, 0, true, true, "2");
    K_ITER(k6 + 5, 2, 1, true, true, "2");
  }
  K_ITER(18, 0, 0, true,  true,  "2");
  K_ITER(19, 1, 1, true,  true,  "2");
  K_ITER(20, 2, 0, true,  true,  "2");
  K_ITER(21, 0, 1, true,  true,  "2");
  K_ITER(22, 1, 0, false, true,  "2");   // A(24) out of range
  K_ITER(23, 2, 1, false, false, "0");   // drain, nothing to issue
#undef K_ITER

  // ---------------- epilogue: LDS transpose (Cs aliases A0+A1) ----------------
  float* Cs = reinterpret_cast<float*>(SM);
  const int chunk = tid & 15;
  const int gcol  = bn * 128 + chunk * 8;
  const f32x4 bias_lo = *reinterpret_cast<const f32x4*>(bias + gcol);
  const f32x4 bias_hi = *reinterpret_cast<const f32x4*>(bias + gcol + 4);

  const int sidx = bm >> 2;        // 4 blocks of 256 rows per 1024-row sample
  const int h  = ss[2 * sidx];
  const int w  = ss[2 * sidx + 1];
  const int hw = h * w;
  const float rh = 16.0f / (float)h;
  const float rw = 16.0f / (float)w;

  for (int sw = 0; sw < 4; ++sw) {
    __syncthreads();               // prior readers (K-loop / prev sweep) done
    if (wr == sw) {
#pragma unroll
      for (int mf = 0; mf < 4; ++mf)
#pragma unroll
        for (int nf = 0; nf < 4; ++nf)
#pragma unroll
          for (int rg = 0; rg < 4; ++rg) {
            const int rowL = mf * 16 + kg * 4 + rg;          // 0..63
            const int col  = wc * 64 + nf * 16 + fr;         // 0..127
            const int key  = (rowL & 3) ^ ((rowL >> 2) & 3);
            Cs[(rowL << 7) + (col ^ (key << 3))] = acc[mf][nf][rg];
          }
    }
    __syncthreads();
#pragma unroll
    for (int pass = 0; pass < 2; ++pass) {
      const int rowL = pass * 32 + (tid >> 4);               // 0..63
      const int key  = (rowL & 3) ^ ((rowL >> 2) & 3);
      const float* crow = Cs + (rowL << 7) + ((chunk ^ key) << 3);
      const f32x4 c0 = *reinterpret_cast<const f32x4*>(crow);
      const f32x4 c1 = *reinterpret_cast<const f32x4*>(crow + 4);

      const int grow = bm * 256 + sw * 64 + rowL;
      int p = grow & 1023;
      if (p >= hw) p = 0;          // padding replicates resized[0] == grid[0,0]
      const int y = p / w;
      const int x = p - y * w;
      const float fy = ((float)y + 0.5f) * rh - 0.5f;
      const float fx = ((float)x + 0.5f) * rw - 0.5f;
      const float yf = floorf(fy), xf = floorf(fx);
      const float ty = fy - yf,   tx = fx - xf;
      int iy0 = (int)yf, ix0 = (int)xf;
      int iy1 = iy0 + 1 > 15 ? 15 : iy0 + 1;
      int ix1 = ix0 + 1 > 15 ? 15 : ix0 + 1;
      iy0 = iy0 < 0 ? 0 : iy0;
      ix0 = ix0 < 0 ? 0 : ix0;
      const float* g00 = pos + (size_t)(iy0 * 16 + ix0) * NDIM + gcol;
      const float* g01 = pos + (size_t)(iy0 * 16 + ix1) * NDIM + gcol;
      const float* g10 = pos + (size_t)(iy1 * 16 + ix0) * NDIM + gcol;
      const float* g11 = pos + (size_t)(iy1 * 16 + ix1) * NDIM + gcol;

      const f32x4 v00l = *reinterpret_cast<const f32x4*>(g00);
      const f32x4 v01l = *reinterpret_cast<const f32x4*>(g01);
      const f32x4 v10l = *reinterpret_cast<const f32x4*>(g10);
      const f32x4 v11l = *reinterpret_cast<const f32x4*>(g11);
      const f32x4 v00h = *reinterpret_cast<const f32x4*>(g00 + 4);
      const f32x4 v01h = *reinterpret_cast<const f32x4*>(g01 + 4);
      const f32x4 v10h = *reinterpret_cast<const f32x4*>(g10 + 4);
      const f32x4 v11h = *reinterpret_cast<const f32x4*>(g11 + 4);

      const f32x4 topl = v00l + tx * (v01l - v00l);
      const f32x4 botl = v10l + tx * (v11l - v10l);
      const f32x4 pvl  = topl + ty * (botl - topl);
      const f32x4 toph = v00h + tx * (v01h - v00h);
      const f32x4 both = v10h + tx * (v11h - v10h);
      const f32x4 pvh  = toph + ty * (both - toph);

      float* orow = out + (size_t)grow * NDIM + gcol;
      *reinterpret_cast<f32x4*>(orow)     = c0 + bias_lo + pvl;
      *reinterpret_cast<f32x4*>(orow + 4) = c1 + bias_hi + pvh;
    }
  }
}

// ---------------- fallback: fp32 inputs, reg-stage + on-the-fly convert (known-good) ----
__global__ __launch_bounds__(256, 2)
void gemm_fb_kernel(const float* __restrict__ A,
                    const int*   __restrict__ ss,
                    const float* __restrict__ Wm,
                    const float* __restrict__ bias,
                    const float* __restrict__ pos,
                    float* __restrict__ out) {
  __shared__ unsigned short As[2][128 * 32];
  __shared__ unsigned short Bs[2][128 * 32];

  const int tid  = threadIdx.x;
  const int lane = tid & 63;
  const int wid  = tid >> 6;
  const int wr   = wid >> 1;
  const int wc   = wid & 1;

  const int bidh = blockIdx.x;
  const int bid  = (bidh & 7) * (FBGRID / 8) + (bidh >> 3);
  const int bm   = bid / NBN;
  const int bn   = bid % NBN;

  const int srow0 = tid >> 3;
  const int skc   = tid & 7;
  const float* Ag = A  + (size_t)(bm * 128 + srow0) * KDIM + skc * 4;
  const float* Bg = Wm + (size_t)(bn * 128 + srow0) * KDIM + skc * 4;

  float4 ra[4], rb[4];

  auto stage_load = [&](int kt) {
    const int ko = kt * 32;
#pragma unroll
    for (int r = 0; r < 4; ++r) {
      ra[r] = *reinterpret_cast<const float4*>(Ag + (size_t)(r * 32) * KDIM + ko);
      rb[r] = *reinterpret_cast<const float4*>(Bg + (size_t)(r * 32) * KDIM + ko);
    }
  };

  auto stage_write = [&](int buf) {
#pragma unroll
    for (int r = 0; r < 4; ++r) {
      const int arow = r * 32 + srow0;
      int off = arow * 64 + skc * 8;
      off ^= (arow & 7) << 4;
      uint2 pa, pb;
      pa.x = pk2(ra[r].x, ra[r].y); pa.y = pk2(ra[r].z, ra[r].w);
      pb.x = pk2(rb[r].x, rb[r].y); pb.y = pk2(rb[r].z, rb[r].w);
      *reinterpret_cast<uint2*>(reinterpret_cast<char*>(&As[buf][0]) + off) = pa;
      *reinterpret_cast<uint2*>(reinterpret_cast<char*>(&Bs[buf][0]) + off) = pb;
    }
  };

  f32x4 acc[4][4];
#pragma unroll
  for (int i = 0; i < 4; ++i)
#pragma unroll
    for (int j = 0; j < 4; ++j) acc[i][j] = (f32x4)0.0f;

  const int fr = lane & 15;
  const int kg = lane >> 4;
  int abase = (wr * 64 + fr) * 64 + kg * 16; abase ^= (fr & 7) << 4;
  int bbase = (wc * 64 + fr) * 64 + kg * 16; bbase ^= (fr & 7) << 4;

  auto compute = [&](int buf) {
    const char* pa = reinterpret_cast<const char*>(&As[buf][0]);
    const char* pb = reinterpret_cast<const char*>(&Bs[buf][0]);
    bf16x8 af[4], bfv[4];
#pragma unroll
    for (int mf = 0; mf < 4; ++mf)
      af[mf] = *reinterpret_cast<const bf16x8*>(pa + abase + mf * 16 * 64);
#pragma unroll
    for (int nf = 0; nf < 4; ++nf)
      bfv[nf] = *reinterpret_cast<const bf16x8*>(pb + bbase + nf * 16 * 64);
#pragma unroll
    for (int mf = 0; mf < 4; ++mf)
#pragma unroll
      for (int nf = 0; nf < 4; ++nf)
        acc[mf][nf] = __builtin_amdgcn_mfma_f32_16x16x32_bf16(af[mf], bfv[nf], acc[mf][nf], 0, 0, 0);
  };

  stage_load(0);
  stage_write(0);
  for (int kt = 0; kt < NKT; ++kt) {
    const int cur = kt & 1;
    if (kt + 1 < NKT) stage_load(kt + 1);
    __syncthreads();
    compute(cur);
    if (kt + 1 < NKT) stage_write(cur ^ 1);
  }

  const int colbase = bn * 128 + wc * 64 + fr;
  float bvals[4];
#pragma unroll
  for (int nf = 0; nf < 4; ++nf) bvals[nf] = bias[colbase + nf * 16];

  const int s  = bm >> 3;
  const int h  = ss[2 * s];
  const int w  = ss[2 * s + 1];
  const int hw = h * w;
  const float rh = 16.0f / (float)h;
  const float rw = 16.0f / (float)w;
  const int row0 = bm * 128 + wr * 64 + kg * 4;

#pragma unroll
  for (int mf = 0; mf < 4; ++mf) {
#pragma unroll
    for (int rg = 0; rg < 4; ++rg) {
      const int row = row0 + mf * 16 + rg;
      int p = row & 1023;
      if (p >= hw) p = 0;
      const int y = p / w;
      const int x = p - y * w;
      const float fy = ((float)y + 0.5f) * rh - 0.5f;
      const float fx = ((float)x + 0.5f) * rw - 0.5f;
      const float yf = floorf(fy), xf = floorf(fx);
      const float ty = fy - yf,   tx = fx - xf;
      int iy0 = (int)yf, ix0 = (int)xf;
      int iy1 = iy0 + 1 > 15 ? 15 : iy0 + 1;
      int ix1 = ix0 + 1 > 15 ? 15 : ix0 + 1;
      iy0 = iy0 < 0 ? 0 : iy0;
      ix0 = ix0 < 0 ? 0 : ix0;
      const float* g00 = pos + (size_t)(iy0 * 16 + ix0) * NDIM;
      const float* g01 = pos + (size_t)(iy0 * 16 + ix1) * NDIM;
      const float* g10 = pos + (size_t)(iy1 * 16 + ix0) * NDIM;
      const float* g11 = pos + (size_t)(iy1 * 16 + ix1) * NDIM;
      float* orow = out + (size_t)row * NDIM;
#pragma unroll
      for (int nf = 0; nf < 4; ++nf) {
        const int col = colbase + nf * 16;
        const float p00 = g00[col], p01 = g01[col];
        const float p10 = g10[col], p11 = g11[col];
        const float top = p00 + tx * (p01 - p00);
        const float bot = p10 + tx * (p11 - p10);
        const float pv  = top + ty * (bot - top);
        orow[col] = acc[mf][nf][rg] + bvals[nf] + pv;
      }
    }
  }
}

extern "C" void kernel_launch(void* const* d_in, const int* in_sizes, int n_in,
                              void* d_out, int out_size, void* d_ws, size_t ws_size,
                              hipStream_t stream) {
  const float* A    = (const float*)d_in[0];
  const int*   ss   = (const int*)d_in[1];
  const float* Wm   = (const float*)d_in[2];
  const float* bias = (const float*)d_in[3];
  const float* pos  = (const float*)d_in[4];
  float* out = (float*)d_out;

  const size_t needA = (size_t)MDIM * KDIM * 2;  // 100,663,296 B
  const size_t needW = (size_t)NDIM * KDIM * 2;  //   1,769,472 B

  if (ws_size >= needA + needW) {
    __bf16* Ab = (__bf16*)d_ws;
    __bf16* Bb = (__bf16*)((char*)d_ws + needA);
    const int chunksA = (MDIM / 16) * NKT * 64;  // 6,291,456 16B chunks
    const int chunksW = (NDIM / 16) * NKT * 64;  //   110,592
    repack_kernel<<<chunksA / 256, 256, 0, stream>>>(A, Ab);
    repack_kernel<<<chunksW / 256, 256, 0, stream>>>(Wm, Bb);
    gemm_8w_kernel<<<GRID2, 512, 0, stream>>>(Ab, Bb, ss, bias, pos, out);
  } else {
    gemm_fb_kernel<<<FBGRID, 256, 0, stream>>>(A, ss, Wm, bias, pos, out);
  }
}

// Round 11
// 272.327 us; speedup vs baseline: 1.0335x; 1.0335x over previous
//
#include <hip/hip_runtime.h>

typedef __bf16 bf16x8 __attribute__((ext_vector_type(8)));
typedef float  f32x4  __attribute__((ext_vector_type(4)));

constexpr int BM = 128, BN = 128, BK = 32;
constexpr int MDIM = 65536, NDIM = 1152, KDIM = 768;
constexpr int NBN = NDIM / BN;          // 9
constexpr int NKT = KDIM / BK;          // 24
constexpr int GRID = (MDIM / BM) * NBN; // 4608 (div by 8 -> bijective XCD swizzle)
constexpr int LDSROWB = BK * 2;         // 64 B per tile row (32 bf16)
constexpr int CHUNKS_A = (MDIM / BM) * NKT * 512;  // 6,291,456 16B chunks
constexpr int CHUNKS_W = NBN * NKT * 512;          //   110,592

__device__ __forceinline__ void gload16(const void* g, void* l) {
  __builtin_amdgcn_global_load_lds(
      (const __attribute__((address_space(1))) void*)g,
      (__attribute__((address_space(3))) void*)l, 16, 0, 0);
}

__device__ __forceinline__ unsigned pk2(float x, float y) {
  __bf16 a = (__bf16)x, b = (__bf16)y;
  return (unsigned)__builtin_bit_cast(unsigned short, a) |
         ((unsigned)__builtin_bit_cast(unsigned short, b) << 16);
}

// ------------- fp32 -> bf16 swizzled-LDS-image repack, A and W in ONE launch -------
__global__ __launch_bounds__(256)
void repack_all_kernel(const float* __restrict__ Ain, __bf16* __restrict__ Aout,
                       const float* __restrict__ Win, __bf16* __restrict__ Wout) {
  int c = blockIdx.x * 256 + threadIdx.x;
  const float* in;
  __bf16* out;
  if (c < CHUNKS_A) { in = Ain; out = Aout; }
  else              { in = Win; out = Wout; c -= CHUNKS_A; }
  const int c_in = c & 511;        // chunk within 8KB image
  const int img  = c >> 9;
  const int kt   = img % NKT;
  const int pan  = img / NKT;      // 128-row panel index
  const int o = c_in * 16;         // swizzled (physical) offset
  const int u = (o >> 6) & 7;
  const int a = o ^ ((u ^ (u >> 2)) << 4);   // invert triangular XOR -> logical addr
  const int r = a >> 6;            // tile row 0..127
  const int p = (a >> 4) & 3;      // 16B part within row
  const float* src = in + (size_t)(pan * 128 + r) * KDIM + kt * 32 + p * 8;
  const float4 x = *reinterpret_cast<const float4*>(src);
  const float4 y = *reinterpret_cast<const float4*>(src + 4);
  uint4 r4;
  r4.x = pk2(x.x, x.y); r4.y = pk2(x.z, x.w);
  r4.z = pk2(y.x, y.y); r4.w = pk2(y.z, y.w);
  *reinterpret_cast<uint4*>(out + (size_t)c * 8) = r4;
}

// ---------------- main GEMM: R3 K-loop + LDS-transpose vectorized epilogue ---------
// (identical structure to R8's 193us kernel; K-loop fully unrolled, scalars hoisted)
__global__ __launch_bounds__(256, 3)
void gemm_swz2_kernel(const __bf16* __restrict__ Aimg,  // [512][24][8KB] swizzled images
                      const __bf16* __restrict__ Bimg,  // [9][24][8KB]
                      const int*   __restrict__ ss,
                      const float* __restrict__ bias,
                      const float* __restrict__ pos,
                      float* __restrict__ out) {
  // single 32 KB pool: tiles during K-loop, fp32 transpose buffer in epilogue
  __shared__ __align__(16) unsigned char SM[32768];
  __bf16* As0 = reinterpret_cast<__bf16*>(SM);            // As[0]: 8KB, As[1]: 8KB
  __bf16* Bs0 = reinterpret_cast<__bf16*>(SM + 16384);    // Bs[0], Bs[1]
  float*  Cs  = reinterpret_cast<float*>(SM);             // 64 x 128 fp32 (epilogue)

  const int tid  = threadIdx.x;
  const int lane = tid & 63;
  const int wid  = tid >> 6;
  const int wr   = wid >> 1;
  const int wc   = wid & 1;

  const int bidh = blockIdx.x;
  const int bid  = (bidh & 7) * (GRID / 8) + (bidh >> 3);
  const int bm   = bid / NBN;
  const int bn   = bid % NBN;

  // hoisted epilogue scalars: latency hides under the K-loop
  const int chunk = tid & 15;
  const int gcol  = bn * BN + chunk * 8;
  const f32x4 bias_lo = *reinterpret_cast<const f32x4*>(bias + gcol);
  const f32x4 bias_hi = *reinterpret_cast<const f32x4*>(bias + gcol + 4);
  const int s  = bm >> 3;
  const int h  = ss[2 * s];
  const int w  = ss[2 * s + 1];
  const int hw = h * w;
  const float rh = 16.0f / (float)h;
  const float rw = 16.0f / (float)w;

  auto stage = [&](int kt, int buf) {
    const __bf16* wsA = Aimg + ((size_t)(bm * NKT + kt) << 12);  // 4096 bf16 / image
    const __bf16* wsB = Bimg + ((size_t)(bn * NKT + kt) << 12);
    char* la = (char*)As0 + buf * 8192;
    char* lb = (char*)Bs0 + buf * 8192;
    gload16(wsA + tid * 8,         la + tid * 16);
    gload16(wsA + (256 + tid) * 8, la + (256 + tid) * 16);
    gload16(wsB + tid * 8,         lb + tid * 16);
    gload16(wsB + (256 + tid) * 8, lb + (256 + tid) * 16);
  };

  f32x4 acc[4][4];
#pragma unroll
  for (int i = 0; i < 4; ++i)
#pragma unroll
    for (int j = 0; j < 4; ++j) acc[i][j] = (f32x4)0.0f;

  const int fr = lane & 15;
  const int kg = lane >> 4;
  const int abase = (((wr * 64 + fr) * LDSROWB) + kg * 16) ^ ((fr & 7) << 4);
  const int bbase = (((wc * 64 + fr) * LDSROWB) + kg * 16) ^ ((fr & 7) << 4);

  auto compute = [&](int buf) {
    const char* pa = (const char*)As0 + buf * 8192;
    const char* pb = (const char*)Bs0 + buf * 8192;
    bf16x8 af[4], bfv[4];
#pragma unroll
    for (int mf = 0; mf < 4; ++mf)
      af[mf] = *reinterpret_cast<const bf16x8*>(pa + abase + mf * 16 * LDSROWB);
#pragma unroll
    for (int nf = 0; nf < 4; ++nf)
      bfv[nf] = *reinterpret_cast<const bf16x8*>(pb + bbase + nf * 16 * LDSROWB);
#pragma unroll
    for (int mf = 0; mf < 4; ++mf)
#pragma unroll
      for (int nf = 0; nf < 4; ++nf)
        acc[mf][nf] = __builtin_amdgcn_mfma_f32_16x16x32_bf16(af[mf], bfv[nf], acc[mf][nf], 0, 0, 0);
  };

  stage(0, 0);
#pragma unroll
  for (int kt = 0; kt < NKT; ++kt) {
    const int cur = kt & 1;
    __syncthreads();                           // drains stage of buf[cur]
    if (kt + 1 < NKT) stage(kt + 1, cur ^ 1);  // async prefetch flies under MFMA
    compute(cur);
  }

  // ------------- epilogue: LDS transpose -> f32x4 pos gathers + full-line stores ----
#pragma unroll
  for (int half = 0; half < 2; ++half) {
    __syncthreads();   // K-loop reads done (half 0) / prev half's reads done (half 1)
    // ---- write phase: col-major acc quads -> swizzled Cs[64][128] ----
#pragma unroll
    for (int mm = 0; mm < 2; ++mm) {
#pragma unroll
      for (int nf = 0; nf < 4; ++nf) {
#pragma unroll
        for (int rg = 0; rg < 4; ++rg) {
          const int rowL = wr * 32 + mm * 16 + kg * 4 + rg;          // 0..63
          const int col  = wc * 64 + nf * 16 + fr;                   // 0..127
          const int key  = (rowL & 3) ^ ((rowL >> 2) & 3);
          Cs[(rowL << 7) + (col ^ (key << 3))] = acc[half * 2 + mm][nf][rg];
        }
      }
    }
    __syncthreads();
    // ---- read + process: 4 passes x (16 rows x 128 cols) ----
#pragma unroll
    for (int pass = 0; pass < 4; ++pass) {
      const int rowL = pass * 16 + (tid >> 4);
      const int key  = (rowL & 3) ^ ((rowL >> 2) & 3);
      const float* crow = Cs + (rowL << 7) + ((chunk ^ key) << 3);
      const f32x4 c0 = *reinterpret_cast<const f32x4*>(crow);
      const f32x4 c1 = *reinterpret_cast<const f32x4*>(crow + 4);

      const int grow = bm * BM + (rowL >> 5) * 64 + half * 32 + (rowL & 31);
      int p = grow & 1023;
      if (p >= hw) p = 0;          // padded region replicates resized[0] == grid[0,0]
      const int y = p / w;
      const int x = p - y * w;
      const float fy = ((float)y + 0.5f) * rh - 0.5f;
      const float fx = ((float)x + 0.5f) * rw - 0.5f;
      const float yf = floorf(fy), xf = floorf(fx);
      const float ty = fy - yf,   tx = fx - xf;
      int iy0 = (int)yf, ix0 = (int)xf;
      int iy1 = iy0 + 1 > 15 ? 15 : iy0 + 1;
      int ix1 = ix0 + 1 > 15 ? 15 : ix0 + 1;
      iy0 = iy0 < 0 ? 0 : iy0;
      ix0 = ix0 < 0 ? 0 : ix0;
      const float* g00 = pos + (size_t)(iy0 * 16 + ix0) * NDIM + gcol;
      const float* g01 = pos + (size_t)(iy0 * 16 + ix1) * NDIM + gcol;
      const float* g10 = pos + (size_t)(iy1 * 16 + ix0) * NDIM + gcol;
      const float* g11 = pos + (size_t)(iy1 * 16 + ix1) * NDIM + gcol;

      const f32x4 v00l = *reinterpret_cast<const f32x4*>(g00);
      const f32x4 v01l = *reinterpret_cast<const f32x4*>(g01);
      const f32x4 v10l = *reinterpret_cast<const f32x4*>(g10);
      const f32x4 v11l = *reinterpret_cast<const f32x4*>(g11);
      const f32x4 v00h = *reinterpret_cast<const f32x4*>(g00 + 4);
      const f32x4 v01h = *reinterpret_cast<const f32x4*>(g01 + 4);
      const f32x4 v10h = *reinterpret_cast<const f32x4*>(g10 + 4);
      const f32x4 v11h = *reinterpret_cast<const f32x4*>(g11 + 4);

      const f32x4 topl = v00l + tx * (v01l - v00l);
      const f32x4 botl = v10l + tx * (v11l - v10l);
      const f32x4 pvl  = topl + ty * (botl - topl);
      const f32x4 toph = v00h + tx * (v01h - v00h);
      const f32x4 both = v10h + tx * (v11h - v10h);
      const f32x4 pvh  = toph + ty * (both - toph);

      float* orow = out + (size_t)grow * NDIM + gcol;
      *reinterpret_cast<f32x4*>(orow)     = c0 + bias_lo + pvl;
      *reinterpret_cast<f32x4*>(orow + 4) = c1 + bias_hi + pvh;
    }
  }
}

// ---------------- fallback: fp32 inputs, reg-stage + on-the-fly convert (known-good) ----
__global__ __launch_bounds__(256, 2)
void gemm_fb_kernel(const float* __restrict__ A,
                    const int*   __restrict__ ss,
                    const float* __restrict__ Wm,
                    const float* __restrict__ bias,
                    const float* __restrict__ pos,
                    float* __restrict__ out) {
  __shared__ unsigned short As[2][BM * BK];
  __shared__ unsigned short Bs[2][BM * BK];

  const int tid  = threadIdx.x;
  const int lane = tid & 63;
  const int wid  = tid >> 6;
  const int wr   = wid >> 1;
  const int wc   = wid & 1;

  const int bidh = blockIdx.x;
  const int bid  = (bidh & 7) * (GRID / 8) + (bidh >> 3);
  const int bm   = bid / NBN;
  const int bn   = bid % NBN;

  const int srow0 = tid >> 3;
  const int skc   = tid & 7;
  const float* Ag = A  + (size_t)(bm * BM + srow0) * KDIM + skc * 4;
  const float* Bg = Wm + (size_t)(bn * BN + srow0) * KDIM + skc * 4;

  float4 ra[4], rb[4];

  auto stage_load = [&](int kt) {
    const int ko = kt * BK;
#pragma unroll
    for (int r = 0; r < 4; ++r) {
      ra[r] = *reinterpret_cast<const float4*>(Ag + (size_t)(r * 32) * KDIM + ko);
      rb[r] = *reinterpret_cast<const float4*>(Bg + (size_t)(r * 32) * KDIM + ko);
    }
  };

  auto stage_write = [&](int buf) {
#pragma unroll
    for (int r = 0; r < 4; ++r) {
      const int arow = r * 32 + srow0;
      int off = arow * LDSROWB + skc * 8;
      off ^= (arow & 7) << 4;
      uint2 pa, pb;
      pa.x = pk2(ra[r].x, ra[r].y); pa.y = pk2(ra[r].z, ra[r].w);
      pb.x = pk2(rb[r].x, rb[r].y); pb.y = pk2(rb[r].z, rb[r].w);
      *reinterpret_cast<uint2*>(reinterpret_cast<char*>(&As[buf][0]) + off) = pa;
      *reinterpret_cast<uint2*>(reinterpret_cast<char*>(&Bs[buf][0]) + off) = pb;
    }
  };

  f32x4 acc[4][4];
#pragma unroll
  for (int i = 0; i < 4; ++i)
#pragma unroll
    for (int j = 0; j < 4; ++j) acc[i][j] = (f32x4)0.0f;

  const int fr = lane & 15;
  const int kg = lane >> 4;
  int abase = (wr * 64 + fr) * LDSROWB + kg * 16; abase ^= (fr & 7) << 4;
  int bbase = (wc * 64 + fr) * LDSROWB + kg * 16; bbase ^= (fr & 7) << 4;

  auto compute = [&](int buf) {
    const char* pa = reinterpret_cast<const char*>(&As[buf][0]);
    const char* pb = reinterpret_cast<const char*>(&Bs[buf][0]);
    bf16x8 af[4], bfv[4];
#pragma unroll
    for (int mf = 0; mf < 4; ++mf)
      af[mf] = *reinterpret_cast<const bf16x8*>(pa + abase + mf * 16 * LDSROWB);
#pragma unroll
    for (int nf = 0; nf < 4; ++nf)
      bfv[nf] = *reinterpret_cast<const bf16x8*>(pb + bbase + nf * 16 * LDSROWB);
#pragma unroll
    for (int mf = 0; mf < 4; ++mf)
#pragma unroll
      for (int nf = 0; nf < 4; ++nf)
        acc[mf][nf] = __builtin_amdgcn_mfma_f32_16x16x32_bf16(af[mf], bfv[nf], acc[mf][nf], 0, 0, 0);
  };

  stage_load(0);
  stage_write(0);
  for (int kt = 0; kt < NKT; ++kt) {
    const int cur = kt & 1;
    if (kt + 1 < NKT) stage_load(kt + 1);
    __syncthreads();
    compute(cur);
    if (kt + 1 < NKT) stage_write(cur ^ 1);
  }

  const int colbase = bn * BN + wc * 64 + fr;
  float bvals[4];
#pragma unroll
  for (int nf = 0; nf < 4; ++nf) bvals[nf] = bias[colbase + nf * 16];

  const int s  = bm >> 3;
  const int h  = ss[2 * s];
  const int w  = ss[2 * s + 1];
  const int hw = h * w;
  const float rh = 16.0f / (float)h;
  const float rw = 16.0f / (float)w;
  const int row0 = bm * BM + wr * 64 + kg * 4;

#pragma unroll
  for (int mf = 0; mf < 4; ++mf) {
#pragma unroll
    for (int rg = 0; rg < 4; ++rg) {
      const int row = row0 + mf * 16 + rg;
      int p = row & 1023;
      if (p >= hw) p = 0;
      const int y = p / w;
      const int x = p - y * w;
      const float fy = ((float)y + 0.5f) * rh - 0.5f;
      const float fx = ((float)x + 0.5f) * rw - 0.5f;
      const float yf = floorf(fy), xf = floorf(fx);
      const float ty = fy - yf,   tx = fx - xf;
      int iy0 = (int)yf, ix0 = (int)xf;
      int iy1 = iy0 + 1 > 15 ? 15 : iy0 + 1;
      int ix1 = ix0 + 1 > 15 ? 15 : ix0 + 1;
      iy0 = iy0 < 0 ? 0 : iy0;
      ix0 = ix0 < 0 ? 0 : ix0;
      const float* g00 = pos + (size_t)(iy0 * 16 + ix0) * NDIM;
      const float* g01 = pos + (size_t)(iy0 * 16 + ix1) * NDIM;
      const float* g10 = pos + (size_t)(iy1 * 16 + ix0) * NDIM;
      const float* g11 = pos + (size_t)(iy1 * 16 + ix1) * NDIM;
      float* orow = out + (size_t)row * NDIM;
#pragma unroll
      for (int nf = 0; nf < 4; ++nf) {
        const int col = colbase + nf * 16;
        const float p00 = g00[col], p01 = g01[col];
        const float p10 = g10[col], p11 = g11[col];
        const float top = p00 + tx * (p01 - p00);
        const float bot = p10 + tx * (p11 - p10);
        const float pv  = top + ty * (bot - top);
        orow[col] = acc[mf][nf][rg] + bvals[nf] + pv;
      }
    }
  }
}

extern "C" void kernel_launch(void* const* d_in, const int* in_sizes, int n_in,
                              void* d_out, int out_size, void* d_ws, size_t ws_size,
                              hipStream_t stream) {
  const float* A    = (const float*)d_in[0];
  const int*   ss   = (const int*)d_in[1];
  const float* Wm   = (const float*)d_in[2];
  const float* bias = (const float*)d_in[3];
  const float* pos  = (const float*)d_in[4];
  float* out = (float*)d_out;

  const size_t needA = (size_t)MDIM * KDIM * 2;  // 100,663,296 B
  const size_t needW = (size_t)NDIM * KDIM * 2;  //   1,769,472 B

  if (ws_size >= needA + needW) {
    __bf16* Ab = (__bf16*)d_ws;
    __bf16* Bb = (__bf16*)((char*)d_ws + needA);
    repack_all_kernel<<<(CHUNKS_A + CHUNKS_W) / 256, 256, 0, stream>>>(A, Ab, Wm, Bb);
    gemm_swz2_kernel<<<GRID, 256, 0, stream>>>(Ab, Bb, ss, bias, pos, out);
  } else {
    gemm_fb_kernel<<<GRID, 256, 0, stream>>>(A, ss, Wm, bias, pos, out);
  }
}

// Round 12
// 259.990 us; speedup vs baseline: 1.0826x; 1.0474x over previous
//
#include <hip/hip_runtime.h>

typedef __bf16 bf16x8 __attribute__((ext_vector_type(8)));
typedef float  f32x4  __attribute__((ext_vector_type(4)));

constexpr int BM = 128, BN = 128, BK = 32;
constexpr int MDIM = 65536, NDIM = 1152, KDIM = 768;
constexpr int NBN = NDIM / BN;          // 9
constexpr int NKT = KDIM / BK;          // 24
constexpr int GRID = (MDIM / BM) * NBN; // 4608 (div by 8 -> bijective XCD swizzle)
constexpr int LDSROWB = BK * 2;         // 64 B per tile row (32 bf16)
constexpr int CHUNKS_A = (MDIM / BM) * NKT * 512;  // 6,291,456 16B chunks
constexpr int CHUNKS_W = NBN * NKT * 512;          //   110,592

__device__ __forceinline__ void gload16(const void* g, void* l) {
  __builtin_amdgcn_global_load_lds(
      (const __attribute__((address_space(1))) void*)g,
      (__attribute__((address_space(3))) void*)l, 16, 0, 0);
}

__device__ __forceinline__ unsigned pk2(float x, float y) {
  __bf16 a = (__bf16)x, b = (__bf16)y;
  return (unsigned)__builtin_bit_cast(unsigned short, a) |
         ((unsigned)__builtin_bit_cast(unsigned short, b) << 16);
}

// ------------- fp32 -> bf16 swizzled-LDS-image repack, A and W in ONE launch -------
__global__ __launch_bounds__(256)
void repack_all_kernel(const float* __restrict__ Ain, __bf16* __restrict__ Aout,
                       const float* __restrict__ Win, __bf16* __restrict__ Wout) {
  int c = blockIdx.x * 256 + threadIdx.x;
  const float* in;
  __bf16* out;
  if (c < CHUNKS_A) { in = Ain; out = Aout; }
  else              { in = Win; out = Wout; c -= CHUNKS_A; }
  const int c_in = c & 511;        // chunk within 8KB image
  const int img  = c >> 9;
  const int kt   = img % NKT;
  const int pan  = img / NKT;      // 128-row panel index
  const int o = c_in * 16;         // swizzled (physical) offset
  const int u = (o >> 6) & 7;
  const int a = o ^ ((u ^ (u >> 2)) << 4);   // invert triangular XOR -> logical addr
  const int r = a >> 6;            // tile row 0..127
  const int p = (a >> 4) & 3;      // 16B part within row
  const float* src = in + (size_t)(pan * 128 + r) * KDIM + kt * 32 + p * 8;
  const float4 x = *reinterpret_cast<const float4*>(src);
  const float4 y = *reinterpret_cast<const float4*>(src + 4);
  uint4 r4;
  r4.x = pk2(x.x, x.y); r4.y = pk2(x.z, x.w);
  r4.z = pk2(y.x, y.y); r4.w = pk2(y.z, y.w);
  *reinterpret_cast<uint4*>(out + (size_t)c * 8) = r4;
}

// ---------------- main GEMM: R8 form verbatim (193us verified) ----------------
__global__ __launch_bounds__(256, 3)
void gemm_swz2_kernel(const __bf16* __restrict__ Aimg,  // [512][24][8KB] swizzled images
                      const __bf16* __restrict__ Bimg,  // [9][24][8KB]
                      const int*   __restrict__ ss,
                      const float* __restrict__ bias,
                      const float* __restrict__ pos,
                      float* __restrict__ out) {
  // single 32 KB pool: tiles during K-loop, fp32 transpose buffer in epilogue
  __shared__ __align__(16) unsigned char SM[32768];
  __bf16* As0 = reinterpret_cast<__bf16*>(SM);            // As[0]: 8KB, As[1]: 8KB
  __bf16* Bs0 = reinterpret_cast<__bf16*>(SM + 16384);    // Bs[0], Bs[1]
  float*  Cs  = reinterpret_cast<float*>(SM);             // 64 x 128 fp32 (epilogue)

  const int tid  = threadIdx.x;
  const int lane = tid & 63;
  const int wid  = tid >> 6;
  const int wr   = wid >> 1;
  const int wc   = wid & 1;

  const int bidh = blockIdx.x;
  const int bid  = (bidh & 7) * (GRID / 8) + (bidh >> 3);
  const int bm   = bid / NBN;
  const int bn   = bid % NBN;

  auto stage = [&](int kt, int buf) {
    const __bf16* wsA = Aimg + ((size_t)(bm * NKT + kt) << 12);  // 4096 bf16 / image
    const __bf16* wsB = Bimg + ((size_t)(bn * NKT + kt) << 12);
    char* la = (char*)As0 + buf * 8192;
    char* lb = (char*)Bs0 + buf * 8192;
    gload16(wsA + tid * 8,         la + tid * 16);
    gload16(wsA + (256 + tid) * 8, la + (256 + tid) * 16);
    gload16(wsB + tid * 8,         lb + tid * 16);
    gload16(wsB + (256 + tid) * 8, lb + (256 + tid) * 16);
  };

  f32x4 acc[4][4];
#pragma unroll
  for (int i = 0; i < 4; ++i)
#pragma unroll
    for (int j = 0; j < 4; ++j) acc[i][j] = (f32x4)0.0f;

  const int fr = lane & 15;
  const int kg = lane >> 4;
  const int abase = (((wr * 64 + fr) * LDSROWB) + kg * 16) ^ ((fr & 7) << 4);
  const int bbase = (((wc * 64 + fr) * LDSROWB) + kg * 16) ^ ((fr & 7) << 4);

  auto compute = [&](int buf) {
    const char* pa = (const char*)As0 + buf * 8192;
    const char* pb = (const char*)Bs0 + buf * 8192;
    bf16x8 af[4], bfv[4];
#pragma unroll
    for (int mf = 0; mf < 4; ++mf)
      af[mf] = *reinterpret_cast<const bf16x8*>(pa + abase + mf * 16 * LDSROWB);
#pragma unroll
    for (int nf = 0; nf < 4; ++nf)
      bfv[nf] = *reinterpret_cast<const bf16x8*>(pb + bbase + nf * 16 * LDSROWB);
#pragma unroll
    for (int mf = 0; mf < 4; ++mf)
#pragma unroll
      for (int nf = 0; nf < 4; ++nf)
        acc[mf][nf] = __builtin_amdgcn_mfma_f32_16x16x32_bf16(af[mf], bfv[nf], acc[mf][nf], 0, 0, 0);
  };

  stage(0, 0);
  for (int kt = 0; kt < NKT; ++kt) {
    const int cur = kt & 1;
    __syncthreads();                           // drains stage of buf[cur]
    if (kt + 1 < NKT) stage(kt + 1, cur ^ 1);  // async prefetch flies under MFMA
    compute(cur);
  }

  // ------------- epilogue: LDS transpose -> f32x4 pos gathers + full-line stores ----
  const int chunk = tid & 15;
  const int gcol  = bn * BN + chunk * 8;
  const f32x4 bias_lo = *reinterpret_cast<const f32x4*>(bias + gcol);
  const f32x4 bias_hi = *reinterpret_cast<const f32x4*>(bias + gcol + 4);

  const int s  = bm >> 3;
  const int h  = ss[2 * s];
  const int w  = ss[2 * s + 1];
  const int hw = h * w;
  const float rh = 16.0f / (float)h;
  const float rw = 16.0f / (float)w;

#pragma unroll
  for (int half = 0; half < 2; ++half) {
    __syncthreads();   // K-loop reads done (half 0) / prev half's reads done (half 1)
    // ---- write phase: col-major acc quads -> swizzled Cs[64][128] ----
#pragma unroll
    for (int mm = 0; mm < 2; ++mm) {
#pragma unroll
      for (int nf = 0; nf < 4; ++nf) {
#pragma unroll
        for (int rg = 0; rg < 4; ++rg) {
          const int rowL = wr * 32 + mm * 16 + kg * 4 + rg;          // 0..63
          const int col  = wc * 64 + nf * 16 + fr;                   // 0..127
          const int key  = (rowL & 3) ^ ((rowL >> 2) & 3);
          Cs[(rowL << 7) + (col ^ (key << 3))] = acc[half * 2 + mm][nf][rg];
        }
      }
    }
    __syncthreads();
    // ---- read + process: 4 passes x (16 rows x 128 cols) ----
#pragma unroll
    for (int pass = 0; pass < 4; ++pass) {
      const int rowL = pass * 16 + (tid >> 4);
      const int key  = (rowL & 3) ^ ((rowL >> 2) & 3);
      const float* crow = Cs + (rowL << 7) + ((chunk ^ key) << 3);
      const f32x4 c0 = *reinterpret_cast<const f32x4*>(crow);
      const f32x4 c1 = *reinterpret_cast<const f32x4*>(crow + 4);

      const int grow = bm * BM + (rowL >> 5) * 64 + half * 32 + (rowL & 31);
      int p = grow & 1023;
      if (p >= hw) p = 0;          // padded region replicates resized[0] == grid[0,0]
      const int y = p / w;
      const int x = p - y * w;
      const float fy = ((float)y + 0.5f) * rh - 0.5f;
      const float fx = ((float)x + 0.5f) * rw - 0.5f;
      const float yf = floorf(fy), xf = floorf(fx);
      const float ty = fy - yf,   tx = fx - xf;
      int iy0 = (int)yf, ix0 = (int)xf;
      int iy1 = iy0 + 1 > 15 ? 15 : iy0 + 1;
      int ix1 = ix0 + 1 > 15 ? 15 : ix0 + 1;
      iy0 = iy0 < 0 ? 0 : iy0;
      ix0 = ix0 < 0 ? 0 : ix0;
      const float* g00 = pos + (size_t)(iy0 * 16 + ix0) * NDIM + gcol;
      const float* g01 = pos + (size_t)(iy0 * 16 + ix1) * NDIM + gcol;
      const float* g10 = pos + (size_t)(iy1 * 16 + ix0) * NDIM + gcol;
      const float* g11 = pos + (size_t)(iy1 * 16 + ix1) * NDIM + gcol;

      const f32x4 v00l = *reinterpret_cast<const f32x4*>(g00);
      const f32x4 v01l = *reinterpret_cast<const f32x4*>(g01);
      const f32x4 v10l = *reinterpret_cast<const f32x4*>(g10);
      const f32x4 v11l = *reinterpret_cast<const f32x4*>(g11);
      const f32x4 v00h = *reinterpret_cast<const f32x4*>(g00 + 4);
      const f32x4 v01h = *reinterpret_cast<const f32x4*>(g01 + 4);
      const f32x4 v10h = *reinterpret_cast<const f32x4*>(g10 + 4);
      const f32x4 v11h = *reinterpret_cast<const f32x4*>(g11 + 4);

      const f32x4 topl = v00l + tx * (v01l - v00l);
      const f32x4 botl = v10l + tx * (v11l - v10l);
      const f32x4 pvl  = topl + ty * (botl - topl);
      const f32x4 toph = v00h + tx * (v01h - v00h);
      const f32x4 both = v10h + tx * (v11h - v10h);
      const f32x4 pvh  = toph + ty * (both - toph);

      float* orow = out + (size_t)grow * NDIM + gcol;
      *reinterpret_cast<f32x4*>(orow)     = c0 + bias_lo + pvl;
      *reinterpret_cast<f32x4*>(orow + 4) = c1 + bias_hi + pvh;
    }
  }
}

// ---------------- fallback: fp32 inputs, reg-stage + on-the-fly convert (known-good) ----
__global__ __launch_bounds__(256, 2)
void gemm_fb_kernel(const float* __restrict__ A,
                    const int*   __restrict__ ss,
                    const float* __restrict__ Wm,
                    const float* __restrict__ bias,
                    const float* __restrict__ pos,
                    float* __restrict__ out) {
  __shared__ unsigned short As[2][BM * BK];
  __shared__ unsigned short Bs[2][BM * BK];

  const int tid  = threadIdx.x;
  const int lane = tid & 63;
  const int wid  = tid >> 6;
  const int wr   = wid >> 1;
  const int wc   = wid & 1;

  const int bidh = blockIdx.x;
  const int bid  = (bidh & 7) * (GRID / 8) + (bidh >> 3);
  const int bm   = bid / NBN;
  const int bn   = bid % NBN;

  const int srow0 = tid >> 3;
  const int skc   = tid & 7;
  const float* Ag = A  + (size_t)(bm * BM + srow0) * KDIM + skc * 4;
  const float* Bg = Wm + (size_t)(bn * BN + srow0) * KDIM + skc * 4;

  float4 ra[4], rb[4];

  auto stage_load = [&](int kt) {
    const int ko = kt * BK;
#pragma unroll
    for (int r = 0; r < 4; ++r) {
      ra[r] = *reinterpret_cast<const float4*>(Ag + (size_t)(r * 32) * KDIM + ko);
      rb[r] = *reinterpret_cast<const float4*>(Bg + (size_t)(r * 32) * KDIM + ko);
    }
  };

  auto stage_write = [&](int buf) {
#pragma unroll
    for (int r = 0; r < 4; ++r) {
      const int arow = r * 32 + srow0;
      int off = arow * LDSROWB + skc * 8;
      off ^= (arow & 7) << 4;
      uint2 pa, pb;
      pa.x = pk2(ra[r].x, ra[r].y); pa.y = pk2(ra[r].z, ra[r].w);
      pb.x = pk2(rb[r].x, rb[r].y); pb.y = pk2(rb[r].z, rb[r].w);
      *reinterpret_cast<uint2*>(reinterpret_cast<char*>(&As[buf][0]) + off) = pa;
      *reinterpret_cast<uint2*>(reinterpret_cast<char*>(&Bs[buf][0]) + off) = pb;
    }
  };

  f32x4 acc[4][4];
#pragma unroll
  for (int i = 0; i < 4; ++i)
#pragma unroll
    for (int j = 0; j < 4; ++j) acc[i][j] = (f32x4)0.0f;

  const int fr = lane & 15;
  const int kg = lane >> 4;
  int abase = (wr * 64 + fr) * LDSROWB + kg * 16; abase ^= (fr & 7) << 4;
  int bbase = (wc * 64 + fr) * LDSROWB + kg * 16; bbase ^= (fr & 7) << 4;

  auto compute = [&](int buf) {
    const char* pa = reinterpret_cast<const char*>(&As[buf][0]);
    const char* pb = reinterpret_cast<const char*>(&Bs[buf][0]);
    bf16x8 af[4], bfv[4];
#pragma unroll
    for (int mf = 0; mf < 4; ++mf)
      af[mf] = *reinterpret_cast<const bf16x8*>(pa + abase + mf * 16 * LDSROWB);
#pragma unroll
    for (int nf = 0; nf < 4; ++nf)
      bfv[nf] = *reinterpret_cast<const bf16x8*>(pb + bbase + nf * 16 * LDSROWB);
#pragma unroll
    for (int mf = 0; mf < 4; ++mf)
#pragma unroll
      for (int nf = 0; nf < 4; ++nf)
        acc[mf][nf] = __builtin_amdgcn_mfma_f32_16x16x32_bf16(af[mf], bfv[nf], acc[mf][nf], 0, 0, 0);
  };

  stage_load(0);
  stage_write(0);
  for (int kt = 0; kt < NKT; ++kt) {
    const int cur = kt & 1;
    if (kt + 1 < NKT) stage_load(kt + 1);
    __syncthreads();
    compute(cur);
    if (kt + 1 < NKT) stage_write(cur ^ 1);
  }

  const int colbase = bn * BN + wc * 64 + fr;
  float bvals[4];
#pragma unroll
  for (int nf = 0; nf < 4; ++nf) bvals[nf] = bias[colbase + nf * 16];

  const int s  = bm >> 3;
  const int h  = ss[2 * s];
  const int w  = ss[2 * s + 1];
  const int hw = h * w;
  const float rh = 16.0f / (float)h;
  const float rw = 16.0f / (float)w;
  const int row0 = bm * BM + wr * 64 + kg * 4;

#pragma unroll
  for (int mf = 0; mf < 4; ++mf) {
#pragma unroll
    for (int rg = 0; rg < 4; ++rg) {
      const int row = row0 + mf * 16 + rg;
      int p = row & 1023;
      if (p >= hw) p = 0;
      const int y = p / w;
      const int x = p - y * w;
      const float fy = ((float)y + 0.5f) * rh - 0.5f;
      const float fx = ((float)x + 0.5f) * rw - 0.5f;
      const float yf = floorf(fy), xf = floorf(fx);
      const float ty = fy - yf,   tx = fx - xf;
      int iy0 = (int)yf, ix0 = (int)xf;
      int iy1 = iy0 + 1 > 15 ? 15 : iy0 + 1;
      int ix1 = ix0 + 1 > 15 ? 15 : ix0 + 1;
      iy0 = iy0 < 0 ? 0 : iy0;
      ix0 = ix0 < 0 ? 0 : ix0;
      const float* g00 = pos + (size_t)(iy0 * 16 + ix0) * NDIM;
      const float* g01 = pos + (size_t)(iy0 * 16 + ix1) * NDIM;
      const float* g10 = pos + (size_t)(iy1 * 16 + ix0) * NDIM;
      const float* g11 = pos + (size_t)(iy1 * 16 + ix1) * NDIM;
      float* orow = out + (size_t)row * NDIM;
#pragma unroll
      for (int nf = 0; nf < 4; ++nf) {
        const int col = colbase + nf * 16;
        const float p00 = g00[col], p01 = g01[col];
        const float p10 = g10[col], p11 = g11[col];
        const float top = p00 + tx * (p01 - p00);
        const float bot = p10 + tx * (p11 - p10);
        const float pv  = top + ty * (bot - top);
        orow[col] = acc[mf][nf][rg] + bvals[nf] + pv;
      }
    }
  }
}

extern "C" void kernel_launch(void* const* d_in, const int* in_sizes, int n_in,
                              void* d_out, int out_size, void* d_ws, size_t ws_size,
                              hipStream_t stream) {
  const float* A    = (const float*)d_in[0];
  const int*   ss   = (const int*)d_in[1];
  const float* Wm   = (const float*)d_in[2];
  const float* bias = (const float*)d_in[3];
  const float* pos  = (const float*)d_in[4];
  float* out = (float*)d_out;

  const size_t needA = (size_t)MDIM * KDIM * 2;  // 100,663,296 B
  const size_t needW = (size_t)NDIM * KDIM * 2;  //   1,769,472 B

  if (ws_size >= needA + needW) {
    __bf16* Ab = (__bf16*)d_ws;
    __bf16* Bb = (__bf16*)((char*)d_ws + needA);
    repack_all_kernel<<<(CHUNKS_A + CHUNKS_W) / 256, 256, 0, stream>>>(A, Ab, Wm, Bb);
    gemm_swz2_kernel<<<GRID, 256, 0, stream>>>(Ab, Bb, ss, bias, pos, out);
  } else {
    gemm_fb_kernel<<<GRID, 256, 0, stream>>>(A, ss, Wm, bias, pos, out);
  }
}